// Round 14
// baseline (181.515 us; speedup 1.0000x reference)
//
#include <hip/hip_runtime.h>
#include <hip/hip_bf16.h>
#include <math.h>

#define NROWS 8192
#define DIM   2048
#define NC    256
#define ALPHA_C 7.18f

typedef float  f32x4  __attribute__((ext_vector_type(4)));
typedef __bf16 bf16x8 __attribute__((ext_vector_type(8)));

// ---------------- workspace layout (bytes) ----------------
#define OFF_A      (size_t)0
#define OFF_DOT    ((size_t)32 << 20)
#define OFF_B      ((size_t)40 << 20)
#define OFF_PERM   ((size_t)41 << 20)
#define OFF_MISC   (OFF_PERM + 32768)
// zero region (37888 B, one memset): gctr | mn2 | scal | hist | lpart | onorm2
#define OFF_GCTR   (OFF_MISC)
#define OFF_MN2    (OFF_MISC + 1024)
#define OFF_SCAL   (OFF_MISC + 2048)
#define OFF_HIST   (OFF_MISC + 3072)
#define OFF_LPART  (OFF_MISC + 4096)
#define OFF_ON2    (OFF_MISC + 5120)
#define ZSIZE      (5120 + 32768)
#define OFF_CNT    (OFF_MISC + ZSIZE)
#define OFF_BASE   (OFF_CNT + 1024)
// scal: [0]=sum_resid(atomic) [1]=num_instances

__device__ __forceinline__ float wave_red_sum(float v) {
#pragma unroll
  for (int off = 32; off > 0; off >>= 1) v += __shfl_xor(v, off, 64);
  return v;
}

// ---------------- histogram of cluster ids (32 blocks) ----------------
__global__ __launch_bounds__(256) void k_hist(const int* __restrict__ clu,
                                              int* __restrict__ hist) {
  __shared__ int h[NC];
  int tid = threadIdx.x;
  h[tid] = 0;
  __syncthreads();
  atomicAdd(&h[clu[blockIdx.x * 256 + tid]], 1);
  __syncthreads();
  if (h[tid]) atomicAdd(&hist[tid], h[tid]);
}

// ---------------- prefix + counts + num_instances (1 tiny block) ----------------
__global__ __launch_bounds__(256) void k_scan(const int* __restrict__ hist,
                                              float* __restrict__ counts,
                                              int* __restrict__ base,
                                              float* scal) {
  __shared__ int pre[NC];
  __shared__ float part[4];
  int tid = threadIdx.x;
  int c = hist[tid];
  counts[tid] = (float)c;
  pre[tid] = c;
  __syncthreads();
  for (int off = 1; off < NC; off <<= 1) {
    int v = (tid >= off) ? pre[tid - off] : 0;
    __syncthreads();
    pre[tid] += v;
    __syncthreads();
  }
  base[tid] = pre[tid] - c;  // exclusive prefix
  float v = (c >= 4) ? (float)c : 0.0f;
  v = wave_red_sum(v);
  if ((tid & 63) == 0) part[tid >> 6] = v;
  __syncthreads();
  if (tid == 0) scal[1] = part[0] + part[1] + part[2] + part[3];
}

// ---------------- build permutation grouping rows by cluster ----------------
__global__ __launch_bounds__(256) void k_perm(const int* __restrict__ clu,
                                              const int* __restrict__ base,
                                              int* __restrict__ gctr,
                                              int* __restrict__ perm) {
  int i = blockIdx.x * 256 + threadIdx.x;
  int c = clu[i];
  int r = atomicAdd(&gctr[c], 1);
  perm[base[c] + r] = i;
}

// ---------------- outputs -> A_swz + onorm2: 1024 blocks (half 16-row tile each) ----------------
__global__ __launch_bounds__(256) void k_conv(const float* __restrict__ out,
                                              bf16x8* __restrict__ A,
                                              float* __restrict__ onorm2) {
  __shared__ float lsum[256];
  int b = blockIdx.x, tid = threadIdx.x;
  int mt = b >> 1, half = b & 1;
  int r = tid & 15;
  const float* rowp = out + ((size_t)mt * 16 + r) * DIM;
  bf16x8* At = A + (size_t)mt * 4096;
  float acc = 0.f;
#pragma unroll
  for (int s2 = 0; s2 < 8; ++s2) {
    int q = (half * 8 + s2) * 256 + tid;
    int kk = q >> 6, lane = q & 63;
    int d = kk * 32 + (lane >> 4) * 8;
    const f32x4* src = (const f32x4*)(rowp + d);
    f32x4 v0 = src[0], v1 = src[1];
    bf16x8 bv;
#pragma unroll
    for (int j = 0; j < 4; ++j) { float f = v0[j]; acc += f * f; bv[j] = (__bf16)f; }
#pragma unroll
    for (int j = 0; j < 4; ++j) { float f = v1[j]; acc += f * f; bv[4 + j] = (__bf16)f; }
    At[q] = bv;
  }
  lsum[tid] = acc;
  __syncthreads();
  if (tid < 16) {
    float s = 0.f;
#pragma unroll
    for (int k = 0; k < 16; ++k) s += lsum[tid + 16 * k];
    atomicAdd(&onorm2[mt * 16 + tid], s);  // onorm2 zero-initialized
  }
}

// ---------------- means via gather-reduce over sorted rows ----------------
__global__ __launch_bounds__(256) void k_msum(const float* __restrict__ out,
                                              const int* __restrict__ perm,
                                              const int* __restrict__ base,
                                              const float* __restrict__ counts,
                                              __bf16* __restrict__ B,
                                              float* __restrict__ mn2) {
  __shared__ int pr[64];
  __shared__ float part[4];
  int bid = blockIdx.x;
  int c = bid >> 3, sl = bid & 7;
  int tid = threadIdx.x;
  int col = sl * 256 + tid;
  int cnt = (int)counts[c];
  int b0 = base[c];
  float acc = 0.f;
  for (int r0 = 0; r0 < cnt; r0 += 64) {
    int lim = min(64, cnt - r0);
    if (tid < lim) pr[tid] = perm[b0 + r0 + tid];
    __syncthreads();
    for (int r = 0; r < lim; ++r) acc += out[(size_t)pr[r] * DIM + col];
    __syncthreads();
  }
  float mean = acc / fmaxf((float)cnt, 1.f);
  int nt = c >> 4, kk = col >> 5, lane = ((col >> 3) & 3) * 16 + (c & 15), j = col & 7;
  B[(((size_t)nt * 64 + kk) * 64 + lane) * 8 + j] = (__bf16)mean;
  float s = mean * mean;
  s = wave_red_sum(s);
  if ((tid & 63) == 0) part[tid >> 6] = s;
  __syncthreads();
  if (tid == 0) atomicAdd(&mn2[c], part[0] + part[1] + part[2] + part[3]);
}

// ---------------- GEMM + resid epilogue: 1024 blocks (4/CU), 32x64 tile, wave = 16x32 ----------------
__global__ __launch_bounds__(256) void k_gemm(const bf16x8* __restrict__ A,
                                              const bf16x8* __restrict__ B,
                                              const int* __restrict__ clu,
                                              const float* __restrict__ counts,
                                              const float* __restrict__ on2v,
                                              const float* __restrict__ mn2,
                                              float* __restrict__ dot,
                                              float* scal) {
  __shared__ float part[4];
  int bid = blockIdx.x;
  int wg = (bid & 7) * 128 + (bid >> 3);  // bijective: 1024 = 8 XCD x 128
  int bm = wg >> 2, bn = wg & 3;          // bm 0..255 (32 rows), bn 0..3 (64 cols)
  int w = threadIdx.x >> 6, l = threadIdx.x & 63;
  int wm = w >> 1, wn = w & 1;
  int mt = bm * 2 + wm;                   // 0..511
  int nt0 = bn * 4 + wn * 2;              // pair {nt0, nt0+1}
  const bf16x8* Ap = A + (size_t)mt * 4096 + l;
  const bf16x8* Bp = B + (size_t)nt0 * 4096 + l;
  f32x4 acc0 = {}, acc1 = {};
#pragma unroll 4
  for (int kk = 0; kk < 64; ++kk) {
    bf16x8 a0 = Ap[kk * 64];
    bf16x8 b0 = Bp[kk * 64];
    bf16x8 b1 = Bp[4096 + kk * 64];
    acc0 = __builtin_amdgcn_mfma_f32_16x16x32_bf16(a0, b0, acc0, 0, 0, 0);
    acc1 = __builtin_amdgcn_mfma_f32_16x16x32_bf16(a0, b1, acc1, 0, 0, 0);
  }
  // C/D layout (m89-verified): col = l&15, row = (l>>4)*4 + reg
  int r0 = bm * 32 + wm * 16 + (l >> 4) * 4;
  int cb = bn * 64 + wn * 32 + (l & 15);
#pragma unroll
  for (int reg = 0; reg < 4; ++reg) {
    float* dst = dot + (size_t)(r0 + reg) * NC + cb;
    dst[0]  = acc0[reg];
    dst[16] = acc1[reg];
  }
  // ---- resid-norm epilogue (phase-A logic, HW-validated round 7) ----
  float rsum = 0.f;
#pragma unroll
  for (int reg = 0; reg < 4; ++reg) {
    int i = r0 + reg;
    int ci = clu[i];
    if (counts[ci] >= 4.0f) {
      if (cb == ci)      rsum += sqrtf(fmaxf(on2v[i] - 2.f * acc0[reg] + mn2[ci], 0.f));
      if (cb + 16 == ci) rsum += sqrtf(fmaxf(on2v[i] - 2.f * acc1[reg] + mn2[ci], 0.f));
    }
  }
  rsum = wave_red_sum(rsum);
  if (l == 0) part[w] = rsum;
  __syncthreads();
  if (threadIdx.x == 0) {
    float t = part[0] + part[1] + part[2] + part[3];
    if (t != 0.f) atomicAdd(&scal[0], t);
  }
}

// ---------------- denom + loss: 2048 blocks (8/CU), 1 row per wave ----------------
__global__ __launch_bounds__(256) void k_denom(const float* __restrict__ dot,
                                               const int* __restrict__ clu,
                                               const float* __restrict__ on2v,
                                               const float* __restrict__ mn2,
                                               const float* __restrict__ counts,
                                               const float* scal,
                                               float* __restrict__ lpart) {
  __shared__ float part[4];
  int w = threadIdx.x >> 6, l = threadIdx.x & 63;
  float s0 = scal[0], s1 = scal[1];
  float cfac = -0.5f * s1 / (s0 * s0);   // = -0.5 / stdev
  f32x4 mn = ((const f32x4*)mn2)[l];
  f32x4 cn = ((const f32x4*)counts)[l];
  int i = blockIdx.x * 4 + w;
  int ci = clu[i];
  float on2 = on2v[i];
  f32x4 dv = ((const f32x4*)(dot + (size_t)i * NC))[l];
  float dsum = 0.f;
#pragma unroll
  for (int j = 0; j < 4; ++j) {
    int cc = l * 4 + j;
    float dist = sqrtf(fmaxf(on2 - 2.f * dv[j] + mn[j], 0.f));
    float e = __expf(cfac * dist);
    dsum += ((cn[j] >= 4.0f) && (cc != ci)) ? e : 0.f;
  }
  dsum = wave_red_sum(dsum);
  float lv = 0.f;
  if (l == 0 && counts[ci] >= 4.0f) {
    float dvi = dot[(size_t)i * NC + ci];
    float rn = sqrtf(fmaxf(on2 - 2.f * dvi + mn2[ci], 0.f));
    lv = __logf(dsum) - (cfac * rn - ALPHA_C);
  }
  if (l == 0) part[w] = lv;
  __syncthreads();
  if (threadIdx.x == 0)
    atomicAdd(&lpart[blockIdx.x & 31], part[0] + part[1] + part[2] + part[3]);
}

__global__ void k_final(const float* scal, const float* lpart, float* out) {
  float s = 0.f;
#pragma unroll
  for (int k = 0; k < 32; ++k) s += lpart[k];
  out[0] = s / scal[1];
}

extern "C" void kernel_launch(void* const* d_in, const int* in_sizes, int n_in,
                              void* d_out, int out_size, void* d_ws, size_t ws_size,
                              hipStream_t stream) {
  const float* outputs = (const float*)d_in[0];
  const int* clusters = (const int*)d_in[1];
  float* out = (float*)d_out;
  char* ws = (char*)d_ws;

  bf16x8* A      = (bf16x8*)(ws + OFF_A);
  float*  dotb   = (float*)(ws + OFF_DOT);
  __bf16* B      = (__bf16*)(ws + OFF_B);
  int*    perm   = (int*)(ws + OFF_PERM);
  int*    gctr   = (int*)(ws + OFF_GCTR);
  float*  mn2    = (float*)(ws + OFF_MN2);
  float*  scal   = (float*)(ws + OFF_SCAL);
  int*    hist   = (int*)(ws + OFF_HIST);
  float*  lpart  = (float*)(ws + OFF_LPART);
  float*  on2    = (float*)(ws + OFF_ON2);
  float*  counts = (float*)(ws + OFF_CNT);
  int*    base   = (int*)(ws + OFF_BASE);

  hipMemsetAsync(ws + OFF_GCTR, 0, ZSIZE, stream);  // gctr, mn2, scal, hist, lpart, on2
  k_hist<<<NROWS / 256, 256, 0, stream>>>(clusters, hist);
  k_scan<<<1, 256, 0, stream>>>(hist, counts, base, scal);
  k_perm<<<NROWS / 256, 256, 0, stream>>>(clusters, base, gctr, perm);
  k_conv<<<NROWS / 8, 256, 0, stream>>>(outputs, A, on2);
  k_msum<<<NC * 8, 256, 0, stream>>>(outputs, perm, base, counts, B, mn2);
  k_gemm<<<1024, 256, 0, stream>>>(A, (const bf16x8*)B, clusters, counts, on2, mn2, dotb, scal);
  k_denom<<<NROWS / 4, 256, 0, stream>>>(dotb, clusters, on2, mn2, counts, scal, lpart);
  k_final<<<1, 1, 0, stream>>>(scal, lpart, out);
}